// Round 4
// baseline (12035.679 us; speedup 1.0000x reference)
//
#include <hip/hip_runtime.h>
#include <hip/hip_cooperative_groups.h>

namespace cg = cooperative_groups;

constexpr int B = 256, T = 512, IN = 8, H = 256, HORIZON = 2;
constexpr int NTHREADS = 512;
constexpr int BT = 32;   // batch rows per workgroup (batch group)
constexpr int HU = 8;    // hidden units per workgroup (=> 32 gate rows/layer)

// LDS weight row stride 260 words (== 4 mod 32 banks): a wave's 8 gx-rows
// start on 8 distinct bank-quads -> conflict-free b128 broadcast reads.
constexpr int LDW = 260;

// transposed h exchange: hT[parity][group][unit(k)][batch], 128B rows
constexpr int GSTR = 256 * 32;     // one group slab
constexpr int PSTR = 8 * GSTR;     // one parity slab

__device__ __forceinline__ float fast_sigmoid(float v) {
    const float e = __expf(-v);
    return __builtin_amdgcn_rcpf(1.f + e);
}
__device__ __forceinline__ float fast_tanh(float v) {
    const float e = __expf(-2.f * v);           // tanh = (1-e)/(1+e)
    return (1.f - e) * __builtin_amdgcn_rcpf(1.f + e);
}

// 16 batch-row-FMAs x 4 gate-cols per 4-k chunk; all indices compile-time.
#define FMA16(E, C)                              \
    acc[0][gi] += hv[E].x * w[gi].C;             \
    acc[1][gi] += hv[E].y * w[gi].C;             \
    acc[2][gi] += hv[E].z * w[gi].C;             \
    acc[3][gi] += hv[E].w * w[gi].C;

// Grid: 256 WGs = 8 batch-groups x 32 hidden-slices, 1 WG/CU (~105 KB LDS).
// Weights: W_ih0/W_hh0/W_ih1 slices in LDS; W_hh1 slice read from global (L2,
// 1 MB/XCD hot) to balance the LDS and VMEM ports. Cell state in registers;
// h exchanged via transposed global slabs. Sync = per-batch-group 32-WG flag
// barrier. Layer-1 runs one step behind layer-0 (both phases full every iter).
__global__ __launch_bounds__(NTHREADS, 2)
void lstm2_kernel(const float* __restrict__ x,
                  const float* __restrict__ Wih0, const float* __restrict__ Whh0,
                  const float* __restrict__ bih0, const float* __restrict__ bhh0,
                  const float* __restrict__ Wih1, const float* __restrict__ Whh1,
                  const float* __restrict__ bih1, const float* __restrict__ bhh1,
                  const float* __restrict__ fcw,  const float* __restrict__ fcb,
                  float* __restrict__ out, float* __restrict__ ws)
{
    __shared__ float sW0x[32][8];        //  1.0 KB  W_ih0 slice
    __shared__ float sW0h[32][LDW];      // 33.3 KB  W_hh0 slice (256 used)
    __shared__ float sW1i[32][LDW];      // 33.3 KB  W_ih1 slice (256 used)
    __shared__ float sB0[32], sB1[32];
    __shared__ float sRed[8][32][36];    // 36.9 KB  k-split partials [ks][g][b]

    const int wg  = blockIdx.x;
    const int bg  = wg & 7;          // same-bg WGs round-robin onto one XCD
    const int hs  = wg >> 3;
    const int bgBase = bg * BT;
    const int hsBase = hs * HU;
    const int tid = threadIdx.x;

    float* hT0 = ws;                 // [2][8][256][32]
    float* hT1 = ws + 2 * PSTR;      // [2][8][256][32]
    unsigned* flags = (unsigned*)(ws + 4 * PSTR);  // [8][32]

    // ---- init barrier flags (ws is re-poisoned before every launch) ----
    if (wg == 0 && tid < 256) flags[tid] = 0;

    // ---- stage weights (once) ----
    for (int idx = tid; idx < 32 * IN; idx += NTHREADS) {
        int r = idx >> 3, j = idx & 7;
        int grow = (r >> 3) * H + hsBase + (r & 7);
        sW0x[r][j] = Wih0[grow * IN + j];
    }
    for (int idx = tid; idx < 32 * 256; idx += NTHREADS) {
        int r = idx >> 8, k = idx & 255;
        int grow = (r >> 3) * H + hsBase + (r & 7);
        sW0h[r][k] = Whh0[grow * H + k];
        sW1i[r][k] = Wih1[grow * H + k];
    }
    if (tid < 32) {
        int grow = (tid >> 3) * H + hsBase + (tid & 7);
        sB0[tid] = bih0[grow] + bhh0[grow];
        sB1[tid] = bih1[grow] + bhh1[grow];
    }
    __syncthreads();

    // one grid-wide sync: publishes flags=0 (and covers staging)
    cg::this_grid().sync();

    // GEMM thread layout: tid = ks*64 + gx*8 + bx. Wave = one ks slice.
    // Thread tile: 4 batches (bx*4..+3, contiguous in hT rows) x 4 gate rows
    // (gi*8+gx). 8 gx lanes broadcast w; 8 bx lanes cover a 128B hT row.
    const int bx = tid & 7;
    const int gx = (tid >> 3) & 7;
    const int ks = tid >> 6;
    const int b0 = bgBase + bx * 4;

    // update threads (tid < 256): one (batch,unit) cell each, state in regs.
    // ub = tid&31 -> 32 consecutive lanes store one contiguous 128B hT row.
    const int ub = tid & 31;
    const int uu = tid >> 5;
    float c0 = 0.f, c1 = 0.f;

    // global W_hh1 row pointers for this thread's 4 gate rows (ks>=4 waves)
    const float* whh1p[4];
    #pragma unroll
    for (int gi = 0; gi < 4; ++gi)
        whh1p[gi] = Whh1 + (size_t)(gi * H + hsBase + gx) * H + (ks & 3) * 64;

    for (int t = 0; t <= T; ++t) {
        // ================= phase 1: layer-1 partials, step s = t-1 =============
        if (t >= 1) {
            const int s = t - 1;
            float acc[4][4];
            #pragma unroll
            for (int i = 0; i < 4; ++i)
                #pragma unroll
                for (int j = 0; j < 4; ++j) acc[i][j] = 0.f;

            if (ks < 4) {
                // h0_s (k cols ks*64..+63) x W_ih1 from LDS
                const float* hb = hT0 + (s & 1) * PSTR + bg * GSTR
                                      + (ks * 64) * 32 + bx * 4;
                const int kw = ks * 64;
                #pragma unroll 4
                for (int kk = 0; kk < 64; kk += 4) {
                    float4 w[4], hv[4];
                    #pragma unroll
                    for (int gi = 0; gi < 4; ++gi)
                        w[gi] = *reinterpret_cast<const float4*>(&sW1i[gi * 8 + gx][kw + kk]);
                    #pragma unroll
                    for (int e = 0; e < 4; ++e)
                        hv[e] = *reinterpret_cast<const float4*>(&hb[(kk + e) * 32]);
                    #pragma unroll
                    for (int gi = 0; gi < 4; ++gi) {
                        FMA16(0, x) FMA16(1, y) FMA16(2, z) FMA16(3, w)
                    }
                }
            } else if (s >= 1) {
                // h1_{s-1} (k cols (ks-4)*64..+63) x W_hh1 from global (L2-hot)
                const float* hb = hT1 + ((s - 1) & 1) * PSTR + bg * GSTR
                                      + ((ks - 4) * 64) * 32 + bx * 4;
                #pragma unroll 4
                for (int kk = 0; kk < 64; kk += 4) {
                    float4 w[4], hv[4];
                    #pragma unroll
                    for (int gi = 0; gi < 4; ++gi)
                        w[gi] = *reinterpret_cast<const float4*>(&whh1p[gi][kk]);
                    #pragma unroll
                    for (int e = 0; e < 4; ++e)
                        hv[e] = *reinterpret_cast<const float4*>(&hb[(kk + e) * 32]);
                    #pragma unroll
                    for (int gi = 0; gi < 4; ++gi) {
                        FMA16(0, x) FMA16(1, y) FMA16(2, z) FMA16(3, w)
                    }
                }
            }
            #pragma unroll
            for (int gi = 0; gi < 4; ++gi)
                *reinterpret_cast<float4*>(&sRed[ks][gi * 8 + gx][bx * 4]) =
                    make_float4(acc[0][gi], acc[1][gi], acc[2][gi], acc[3][gi]);
        }
        __syncthreads();
        // ---- layer-1 reduce + cell update ----
        if (t >= 1 && tid < 256) {
            const int s = t - 1;
            float g4[4];
            #pragma unroll
            for (int gt = 0; gt < 4; ++gt) {
                const int gl = gt * 8 + uu;
                float sum = sB1[gl];
                #pragma unroll
                for (int k = 0; k < 8; ++k) sum += sRed[k][gl][ub];
                g4[gt] = sum;
            }
            const float ig = fast_sigmoid(g4[0]);
            const float fg = fast_sigmoid(g4[1]);
            const float gg = fast_tanh(g4[2]);
            const float og = fast_sigmoid(g4[3]);
            c1 = fg * c1 + ig * gg;
            const float hv = og * fast_tanh(c1);
            hT1[(s & 1) * PSTR + bg * GSTR + (hsBase + uu) * 32 + ub] = hv;
        }
        __syncthreads();
        // ================= phase 2: layer-0 partials, step t ===================
        if (t < T) {
            float acc[4][4];
            #pragma unroll
            for (int i = 0; i < 4; ++i)
                #pragma unroll
                for (int j = 0; j < 4; ++j) acc[i][j] = 0.f;

            if (t >= 1) {  // h-part (h0_{t-1}); at t==0 h0_prev == 0
                const float* hb = hT0 + ((t - 1) & 1) * PSTR + bg * GSTR
                                      + (ks * 32) * 32 + bx * 4;
                const int kw = ks * 32;
                #pragma unroll 4
                for (int kk = 0; kk < 32; kk += 4) {
                    float4 w[4], hv[4];
                    #pragma unroll
                    for (int gi = 0; gi < 4; ++gi)
                        w[gi] = *reinterpret_cast<const float4*>(&sW0h[gi * 8 + gx][kw + kk]);
                    #pragma unroll
                    for (int e = 0; e < 4; ++e)
                        hv[e] = *reinterpret_cast<const float4*>(&hb[(kk + e) * 32]);
                    #pragma unroll
                    for (int gi = 0; gi < 4; ++gi) {
                        FMA16(0, x) FMA16(1, y) FMA16(2, z) FMA16(3, w)
                    }
                }
            }
            if (ks == 0) {  // x-projection part, K=8 (x is batch-major)
                #pragma unroll
                for (int j = 0; j < IN; j += 4) {
                    float4 w[4], xv[4];
                    #pragma unroll
                    for (int gi = 0; gi < 4; ++gi)
                        w[gi] = *reinterpret_cast<const float4*>(&sW0x[gi * 8 + gx][j]);
                    #pragma unroll
                    for (int bi = 0; bi < 4; ++bi)
                        xv[bi] = *reinterpret_cast<const float4*>(
                                     &x[((size_t)(b0 + bi) * T + t) * IN + j]);
                    #pragma unroll
                    for (int gi = 0; gi < 4; ++gi) {
                        #pragma unroll
                        for (int bi = 0; bi < 4; ++bi) {
                            acc[bi][gi] += xv[bi].x * w[gi].x;
                            acc[bi][gi] += xv[bi].y * w[gi].y;
                            acc[bi][gi] += xv[bi].z * w[gi].z;
                            acc[bi][gi] += xv[bi].w * w[gi].w;
                        }
                    }
                }
            }
            #pragma unroll
            for (int gi = 0; gi < 4; ++gi)
                *reinterpret_cast<float4*>(&sRed[ks][gi * 8 + gx][bx * 4]) =
                    make_float4(acc[0][gi], acc[1][gi], acc[2][gi], acc[3][gi]);
        }
        __syncthreads();
        // ---- layer-0 reduce + cell update ----
        if (t < T && tid < 256) {
            float g4[4];
            #pragma unroll
            for (int gt = 0; gt < 4; ++gt) {
                const int gl = gt * 8 + uu;
                float sum = sB0[gl];
                #pragma unroll
                for (int k = 0; k < 8; ++k) sum += sRed[k][gl][ub];
                g4[gt] = sum;
            }
            const float ig = fast_sigmoid(g4[0]);
            const float fg = fast_sigmoid(g4[1]);
            const float gg = fast_tanh(g4[2]);
            const float og = fast_sigmoid(g4[3]);
            c0 = fg * c0 + ig * gg;
            const float hv = og * fast_tanh(c0);
            hT0[(t & 1) * PSTR + bg * GSTR + (hsBase + uu) * 32 + ub] = hv;
        }
        // ---- 32-WG batch-group barrier: per-WG flag + 32-lane poll ----
        __syncthreads();                     // block's h stores drained (vmcnt 0)
        if (tid < 64) {
            const unsigned tgt = (unsigned)(t + 1);
            if (tid == 0) {
                __threadfence();             // publish h at agent scope
                __hip_atomic_store(&flags[bg * 32 + hs], tgt,
                                   __ATOMIC_RELEASE, __HIP_MEMORY_SCOPE_AGENT);
            }
            while (true) {
                unsigned v = tgt;
                if (tid < 32)
                    v = __hip_atomic_load(&flags[bg * 32 + tid],
                                          __ATOMIC_ACQUIRE, __HIP_MEMORY_SCOPE_AGENT);
                if (__all((int)(v >= tgt))) break;
                __builtin_amdgcn_s_sleep(1);
            }
            __threadfence();                 // invalidate stale caches for h reads
        }
        __syncthreads();
    }

    // ================= FC head: out = h1[T-1] @ fcw^T + fcb ===================
    if (hs == 0 && tid < BT * HORIZON) {
        const int bb = tid >> 1, hz = tid & 1;
        const float* hcol = hT1 + ((T - 1) & 1) * PSTR + bg * GSTR + bb;
        float acc = fcb[hz];
        for (int u = 0; u < H; ++u)
            acc += fcw[hz * H + u] * hcol[u * 32];
        out[(bgBase + bb) * HORIZON + hz] = acc;   // (B, HORIZON, 1) flat
    }
}

extern "C" void kernel_launch(void* const* d_in, const int* in_sizes, int n_in,
                              void* d_out, int out_size, void* d_ws, size_t ws_size,
                              hipStream_t stream) {
    const float* x    = (const float*)d_in[0];
    const float* Wih0 = (const float*)d_in[1];
    const float* Whh0 = (const float*)d_in[2];
    const float* bih0 = (const float*)d_in[3];
    const float* bhh0 = (const float*)d_in[4];
    const float* Wih1 = (const float*)d_in[5];
    const float* Whh1 = (const float*)d_in[6];
    const float* bih1 = (const float*)d_in[7];
    const float* bhh1 = (const float*)d_in[8];
    const float* fcw  = (const float*)d_in[9];
    const float* fcb  = (const float*)d_in[10];
    float* out = (float*)d_out;
    float* ws  = (float*)d_ws;   // 4*PSTR floats + 256 uints ≈ 1 MB

    void* args[] = { &x, &Wih0, &Whh0, &bih0, &bhh0, &Wih1, &Whh1, &bih1, &bhh1,
                     &fcw, &fcb, &out, &ws };
    hipLaunchCooperativeKernel((const void*)lstm2_kernel,
                               dim3(256), dim3(NTHREADS), args, 0, stream);
}

// Round 7
// 8890.865 us; speedup vs baseline: 1.3537x; 1.3537x over previous
//
#include <hip/hip_runtime.h>
#include <hip/hip_cooperative_groups.h>

namespace cg = cooperative_groups;

constexpr int B = 256, T = 512, IN = 8, H = 256, HORIZON = 2;
constexpr int NTHREADS = 512;
constexpr int BT = 32;   // batch rows per workgroup (batch group)
constexpr int HU = 8;    // hidden units per workgroup (=> 32 gate rows/layer)

// LDS weight row stride 260 words (== 4 mod 32 banks): a wave's 8 gx-rows
// start on 8 distinct bank-quads -> conflict-free b128 broadcast reads.
constexpr int LDW = 260;

// transposed h exchange: hT[parity][group][unit(k)][batch], 128B rows
constexpr int GSTR = 256 * 32;     // one group slab
constexpr int PSTR = 8 * GSTR;     // one parity slab

__device__ __forceinline__ float fast_sigmoid(float v) {
    const float e = __expf(-v);
    return __builtin_amdgcn_rcpf(1.f + e);
}
__device__ __forceinline__ float fast_tanh(float v) {
    const float e = __expf(-2.f * v);           // tanh = (1-e)/(1+e)
    return (1.f - e) * __builtin_amdgcn_rcpf(1.f + e);
}

// Relaxed agent-scope 4B access: per-address coherence-point load/store
// (global_load/store_dword sc1). NO bulk wbl2/inv -> L2 weight residency
// survives across steps (R4's 85% stall was the per-step fence pair).
// Release: h_store is a coherence-point write; __syncthreads() drains
// vmcnt(0), so the flag store issues only after all h is globally visible.
// Acquire: sc1 loads can't hit stale L1/L2; h loads issue after flag wait.
__device__ __forceinline__ float h_load(const float* p) {
    return __hip_atomic_load(p, __ATOMIC_RELAXED, __HIP_MEMORY_SCOPE_AGENT);
}
__device__ __forceinline__ void h_store(float* p, float v) {
    __hip_atomic_store(p, v, __ATOMIC_RELAXED, __HIP_MEMORY_SCOPE_AGENT);
}

// 16 batch-row-FMAs x 4 gate-cols per 4-k chunk; all indices compile-time.
#define FMA16(E, C)                              \
    acc[0][gi] += hv[E].x * w[gi].C;             \
    acc[1][gi] += hv[E].y * w[gi].C;             \
    acc[2][gi] += hv[E].z * w[gi].C;             \
    acc[3][gi] += hv[E].w * w[gi].C;

// Grid: 256 WGs = 8 batch-groups x 32 hidden-slices, 1 WG/CU (~135 KB LDS).
// W_ih0/W_hh0 slices in LDS; W_ih1/W_hh1 read from global (stay L2-resident --
// nothing invalidates L2 anymore). Cell state in registers. h exchanged via
// relaxed agent atomics through global slabs, staged into LDS once per step.
// Sync = per-batch-group 32-WG flag barrier, fence-free.
__global__ __launch_bounds__(NTHREADS, 2)
void lstm2_kernel(const float* __restrict__ x,
                  const float* __restrict__ Wih0, const float* __restrict__ Whh0,
                  const float* __restrict__ bih0, const float* __restrict__ bhh0,
                  const float* __restrict__ Wih1, const float* __restrict__ Whh1,
                  const float* __restrict__ bih1, const float* __restrict__ bhh1,
                  const float* __restrict__ fcw,  const float* __restrict__ fcb,
                  float* __restrict__ out, float* __restrict__ ws)
{
    __shared__ float sW0x[32][8];        //  1.0 KB  W_ih0 slice
    __shared__ float sW0h[32][LDW];      // 33.3 KB  W_hh0 slice (256 used)
    __shared__ float sB0[32], sB1[32];
    __shared__ float sRed[8][32][36];    // 36.9 KB  k-split partials [ks][g][b]
    __shared__ float sH0[256][32];       // 32.0 KB  staged h0(t-1) [k][batch]
    __shared__ float sH1[256][32];       // 32.0 KB  staged h1(t-2) [k][batch]

    const int wg  = blockIdx.x;
    const int bg  = wg & 7;
    const int hs  = wg >> 3;
    const int bgBase = bg * BT;
    const int hsBase = hs * HU;
    const int tid = threadIdx.x;

    float* hT0 = ws;                 // [2][8][256][32]
    float* hT1 = ws + 2 * PSTR;      // [2][8][256][32]
    unsigned* flags = (unsigned*)(ws + 4 * PSTR);  // [8][32]

    // ---- init barrier flags (ws is re-poisoned before every launch) ----
    if (wg == 0 && tid < 256) flags[tid] = 0;

    // ---- stage LDS weights (once) ----
    for (int idx = tid; idx < 32 * IN; idx += NTHREADS) {
        int r = idx >> 3, j = idx & 7;
        int grow = (r >> 3) * H + hsBase + (r & 7);
        sW0x[r][j] = Wih0[grow * IN + j];
    }
    for (int idx = tid; idx < 32 * 256; idx += NTHREADS) {
        int r = idx >> 8, k = idx & 255;
        int grow = (r >> 3) * H + hsBase + (r & 7);
        sW0h[r][k] = Whh0[grow * H + k];
    }
    if (tid < 32) {
        int grow = (tid >> 3) * H + hsBase + (tid & 7);
        sB0[tid] = bih0[grow] + bhh0[grow];
        sB1[tid] = bih1[grow] + bhh1[grow];
    }
    __syncthreads();

    // one grid-wide sync: publishes flags=0 to all XCDs (only bulk fence pair)
    cg::this_grid().sync();

    // GEMM thread layout: tid = ks*64 + gx*8 + bx. Wave = one ks slice.
    // Thread tile: 4 batches (bx*4..+3, contiguous in sH rows) x 4 gate rows
    // (gi*8+gx). 8 gx lanes broadcast w; 8 bx lanes cover a 128B sH row.
    const int bx = tid & 7;
    const int gx = (tid >> 3) & 7;
    const int ks = tid >> 6;
    const int b0 = bgBase + bx * 4;

    // layer-1 weight row pointers (global, L2-hot): ks<4 -> W_ih1 (vs h0),
    // ks>=4 -> W_hh1 (vs h1). Wave-uniform choice, no divergence.
    const float* wp[4];
    #pragma unroll
    for (int gi = 0; gi < 4; ++gi)
        wp[gi] = ((ks < 4) ? Wih1 : Whh1)
               + (size_t)(gi * H + hsBase + gx) * H + (ks & 3) * 64;
    // staged-h base for phase 1 (wave-uniform)
    const float* hbase1 = (ks < 4) ? &sH0[ks * 64][0] : &sH1[(ks & 3) * 64][0];

    // update threads (tid < 256): one (batch,unit) cell each, state in regs.
    const int ub = tid & 31;
    const int uu = tid >> 5;
    float c0 = 0.f, c1 = 0.f;

    for (int t = 0; t <= T; ++t) {
        // ---- stage h slabs for this iteration (coherence-point -> LDS) ----
        if (t >= 1) {
            const float* src = hT0 + ((t - 1) & 1) * PSTR + bg * GSTR;
            #pragma unroll
            for (int i = 0; i < 16; ++i) {
                int idx = tid + i * NTHREADS;     // coalesced 128B rows
                sH0[idx >> 5][idx & 31] = h_load(&src[idx]);
            }
        }
        if (t >= 2) {
            const float* src = hT1 + (t & 1) * PSTR + bg * GSTR;
            #pragma unroll
            for (int i = 0; i < 16; ++i) {
                int idx = tid + i * NTHREADS;
                sH1[idx >> 5][idx & 31] = h_load(&src[idx]);
            }
        }
        __syncthreads();

        // ================= phase 1: layer-1 partials, step s = t-1 =============
        if (t >= 1) {
            const int s = t - 1;
            float acc[4][4];
            #pragma unroll
            for (int i = 0; i < 4; ++i)
                #pragma unroll
                for (int j = 0; j < 4; ++j) acc[i][j] = 0.f;

            if (ks < 4 || s >= 1) {   // ks>=4 needs h1_{s-1}, absent at s==0
                #pragma unroll 4
                for (int kk = 0; kk < 64; kk += 4) {
                    float4 w[4], hv[4];
                    #pragma unroll
                    for (int gi = 0; gi < 4; ++gi)
                        w[gi] = *reinterpret_cast<const float4*>(&wp[gi][kk]);
                    #pragma unroll
                    for (int e = 0; e < 4; ++e)
                        hv[e] = *reinterpret_cast<const float4*>(
                                    &hbase1[(kk + e) * 32 + bx * 4]);
                    #pragma unroll
                    for (int gi = 0; gi < 4; ++gi) {
                        FMA16(0, x) FMA16(1, y) FMA16(2, z) FMA16(3, w)
                    }
                }
            }
            #pragma unroll
            for (int gi = 0; gi < 4; ++gi)
                *reinterpret_cast<float4*>(&sRed[ks][gi * 8 + gx][bx * 4]) =
                    make_float4(acc[0][gi], acc[1][gi], acc[2][gi], acc[3][gi]);
        }
        __syncthreads();
        // ---- layer-1 reduce + cell update ----
        if (t >= 1 && tid < 256) {
            const int s = t - 1;
            float g4[4];
            #pragma unroll
            for (int gt = 0; gt < 4; ++gt) {
                const int gl = gt * 8 + uu;
                float sum = sB1[gl];
                #pragma unroll
                for (int k = 0; k < 8; ++k) sum += sRed[k][gl][ub];
                g4[gt] = sum;
            }
            const float ig = fast_sigmoid(g4[0]);
            const float fg = fast_sigmoid(g4[1]);
            const float gg = fast_tanh(g4[2]);
            const float og = fast_sigmoid(g4[3]);
            c1 = fg * c1 + ig * gg;
            const float hv = og * fast_tanh(c1);
            h_store(&hT1[(s & 1) * PSTR + bg * GSTR + (hsBase + uu) * 32 + ub], hv);
        }
        __syncthreads();
        // ================= phase 2: layer-0 partials, step t ===================
        if (t < T) {
            float acc[4][4];
            #pragma unroll
            for (int i = 0; i < 4; ++i)
                #pragma unroll
                for (int j = 0; j < 4; ++j) acc[i][j] = 0.f;

            if (t >= 1) {  // h-part (h0_{t-1}); at t==0 h0_prev == 0
                const float* hb = &sH0[ks * 32][0];
                const int kw = ks * 32;
                #pragma unroll 4
                for (int kk = 0; kk < 32; kk += 4) {
                    float4 w[4], hv[4];
                    #pragma unroll
                    for (int gi = 0; gi < 4; ++gi)
                        w[gi] = *reinterpret_cast<const float4*>(&sW0h[gi * 8 + gx][kw + kk]);
                    #pragma unroll
                    for (int e = 0; e < 4; ++e)
                        hv[e] = *reinterpret_cast<const float4*>(
                                    &hb[(kk + e) * 32 + bx * 4]);
                    #pragma unroll
                    for (int gi = 0; gi < 4; ++gi) {
                        FMA16(0, x) FMA16(1, y) FMA16(2, z) FMA16(3, w)
                    }
                }
            }
            if (ks == 0) {  // x-projection part, K=8 (x is batch-major)
                #pragma unroll
                for (int j = 0; j < IN; j += 4) {
                    float4 w[4], xv[4];
                    #pragma unroll
                    for (int gi = 0; gi < 4; ++gi)
                        w[gi] = *reinterpret_cast<const float4*>(&sW0x[gi * 8 + gx][j]);
                    #pragma unroll
                    for (int bi = 0; bi < 4; ++bi)
                        xv[bi] = *reinterpret_cast<const float4*>(
                                     &x[((size_t)(b0 + bi) * T + t) * IN + j]);
                    #pragma unroll
                    for (int gi = 0; gi < 4; ++gi) {
                        #pragma unroll
                        for (int bi = 0; bi < 4; ++bi) {
                            acc[bi][gi] += xv[bi].x * w[gi].x;
                            acc[bi][gi] += xv[bi].y * w[gi].y;
                            acc[bi][gi] += xv[bi].z * w[gi].z;
                            acc[bi][gi] += xv[bi].w * w[gi].w;
                        }
                    }
                }
            }
            #pragma unroll
            for (int gi = 0; gi < 4; ++gi)
                *reinterpret_cast<float4*>(&sRed[ks][gi * 8 + gx][bx * 4]) =
                    make_float4(acc[0][gi], acc[1][gi], acc[2][gi], acc[3][gi]);
        }
        __syncthreads();
        // ---- layer-0 reduce + cell update ----
        if (t < T && tid < 256) {
            float g4[4];
            #pragma unroll
            for (int gt = 0; gt < 4; ++gt) {
                const int gl = gt * 8 + uu;
                float sum = sB0[gl];
                #pragma unroll
                for (int k = 0; k < 8; ++k) sum += sRed[k][gl][ub];
                g4[gt] = sum;
            }
            const float ig = fast_sigmoid(g4[0]);
            const float fg = fast_sigmoid(g4[1]);
            const float gg = fast_tanh(g4[2]);
            const float og = fast_sigmoid(g4[3]);
            c0 = fg * c0 + ig * gg;
            const float hv = og * fast_tanh(c0);
            h_store(&hT0[(t & 1) * PSTR + bg * GSTR + (hsBase + uu) * 32 + ub], hv);
        }
        // ---- 32-WG batch-group barrier: fence-free flag protocol ----
        // __syncthreads drains vmcnt for ALL waves -> every h sc-store of this
        // WG is at the coherence point before the flag store issues.
        __syncthreads();
        if (tid < 64) {
            const unsigned tgt = (unsigned)(t + 1);
            if (tid == 0)
                __hip_atomic_store(&flags[bg * 32 + hs], tgt,
                                   __ATOMIC_RELAXED, __HIP_MEMORY_SCOPE_AGENT);
            while (true) {
                unsigned v = tgt;
                if (tid < 32)
                    v = __hip_atomic_load(&flags[bg * 32 + tid],
                                          __ATOMIC_RELAXED, __HIP_MEMORY_SCOPE_AGENT);
                if (__all((int)(v >= tgt))) break;
                __builtin_amdgcn_s_sleep(1);
            }
        }
        __syncthreads();
    }

    // ================= FC head: out = h1[T-1] @ fcw^T + fcb ===================
    if (hs == 0 && tid < BT * HORIZON) {
        const int bb = tid >> 1, hz = tid & 1;
        const float* hcol = hT1 + ((T - 1) & 1) * PSTR + bg * GSTR + bb;
        float acc = fcb[hz];
        for (int u = 0; u < H; ++u)
            acc += fcw[hz * H + u] * h_load(&hcol[u * 32]);
        out[(bgBase + bb) * HORIZON + hz] = acc;   // (B, HORIZON, 1) flat
    }
}

extern "C" void kernel_launch(void* const* d_in, const int* in_sizes, int n_in,
                              void* d_out, int out_size, void* d_ws, size_t ws_size,
                              hipStream_t stream) {
    const float* x    = (const float*)d_in[0];
    const float* Wih0 = (const float*)d_in[1];
    const float* Whh0 = (const float*)d_in[2];
    const float* bih0 = (const float*)d_in[3];
    const float* bhh0 = (const float*)d_in[4];
    const float* Wih1 = (const float*)d_in[5];
    const float* Whh1 = (const float*)d_in[6];
    const float* bih1 = (const float*)d_in[7];
    const float* bhh1 = (const float*)d_in[8];
    const float* fcw  = (const float*)d_in[9];
    const float* fcb  = (const float*)d_in[10];
    float* out = (float*)d_out;
    float* ws  = (float*)d_ws;   // 4*PSTR floats + 256 uints ≈ 1 MB

    void* args[] = { &x, &Wih0, &Whh0, &bih0, &bhh0, &Wih1, &Whh1, &bih1, &bhh1,
                     &fcw, &fcb, &out, &ws };
    hipLaunchCooperativeKernel((const void*)lstm2_kernel,
                               dim3(256), dim3(NTHREADS), args, 0, stream);
}